// Round 4
// baseline (3837.310 us; speedup 1.0000x reference)
//
#include <hip/hip_runtime.h>

#define S_LEN 768
#define EMB   128
#define HDIM  256
#define GATES 1024
#define MLP   128
#define SENT  0xAAAAAAAAu

// ---------------- embedding gather ----------------
__global__ void embed_kernel(const int* __restrict__ widx, const int* __restrict__ pidx,
                             const float* __restrict__ Ww, const float* __restrict__ Wp,
                             float* __restrict__ x0) {
    int t = blockIdx.x, k = threadIdx.x;
    float v;
    if (k < 100) v = Ww[widx[t] * 100 + k];
    else         v = Wp[pidx[t] * 28 + (k - 100)];
    x0[t * EMB + k] = v;
}

// ---------------- generic fp32 GEMM: C[M,N] = A[M,*] * B[N,*]^T + bias1 + bias2 ----------------
__global__ __launch_bounds__(256) void gemm_bias(
    const float* __restrict__ A, int lda,
    const float* __restrict__ B, int ldb,
    const float* __restrict__ bias1, const float* __restrict__ bias2,
    float* __restrict__ C, int ldc, int K) {
    __shared__ float As[32][65];
    __shared__ float Bs[32][65];
    const int t  = threadIdx.x;
    const int m0 = blockIdx.x * 64, n0 = blockIdx.y * 64;
    const int tm = t >> 4, tn = t & 15;
    float acc[4][4];
#pragma unroll
    for (int i = 0; i < 4; ++i)
#pragma unroll
        for (int j = 0; j < 4; ++j) acc[i][j] = 0.f;

    for (int k0 = 0; k0 < K; k0 += 32) {
#pragma unroll
        for (int l = 0; l < 8; ++l) {
            int idx = t + l * 256;
            int m = idx >> 5, kk = idx & 31;
            As[kk][m] = A[(m0 + m) * lda + k0 + kk];
            Bs[kk][m] = B[(n0 + m) * ldb + k0 + kk];
        }
        __syncthreads();
#pragma unroll
        for (int kk = 0; kk < 32; ++kk) {
            float a4[4], b4[4];
#pragma unroll
            for (int i = 0; i < 4; ++i) a4[i] = As[kk][tm * 4 + i];
#pragma unroll
            for (int j = 0; j < 4; ++j) b4[j] = Bs[kk][tn * 4 + j];
#pragma unroll
            for (int i = 0; i < 4; ++i)
#pragma unroll
                for (int j = 0; j < 4; ++j)
                    acc[i][j] = fmaf(a4[i], b4[j], acc[i][j]);
        }
        __syncthreads();
    }
    float bb[4];
#pragma unroll
    for (int j = 0; j < 4; ++j) {
        int n = n0 + tn * 4 + j;
        bb[j] = (bias1 ? bias1[n] : 0.f) + (bias2 ? bias2[n] : 0.f);
    }
#pragma unroll
    for (int i = 0; i < 4; ++i) {
        int m = m0 + tm * 4 + i;
        float4 o;
        o.x = acc[i][0] + bb[0];
        o.y = acc[i][1] + bb[1];
        o.z = acc[i][2] + bb[2];
        o.w = acc[i][3] + bb[3];
        *(float4*)(&C[m * ldc + n0 + tn * 4]) = o;
    }
}

// ---------------- LSTM recurrence, one layer, both directions ----------------
// 16 blocks x 512 threads: dir = bid&1, slice sl = bid>>1 (8 slices/dir).
// Block covers 128 gate rows (4 gates x 32 h-elems); 4 threads per row,
// 16 float4 (=64 VGPRs) of Whh each -- small enough that the register
// allocator keeps them resident (R1/R3: 128-reg variant was spilled/reloaded).
// Sync: data-as-flag through agent scope (h word != 0xAA sentinel).
__global__ __launch_bounds__(512, 1) void lstm_rec(
    const float* __restrict__ WhhF, const float* __restrict__ WhhB,
    const float* __restrict__ gxF, const float* __restrict__ gxB,
    float* __restrict__ hOut)        // [S][512]; fwd cols 0..255, bwd 256..511
{
    __shared__ float hp[HDIM];
    __shared__ float gl[128];
    __shared__ float cl[32];
    const int tid = threadIdx.x;
    const int dir = blockIdx.x & 1;
    const int sl  = blockIdx.x >> 1;
    const float* __restrict__ Whh = dir ? WhhB : WhhF;
    const float* __restrict__ gx  = dir ? gxB  : gxF;
    unsigned int* hbits = (unsigned int*)hOut;

    const int r = tid >> 2, q = tid & 3;            // row 0..127, quarter 0..3
    const int grow = ((r >> 5) << 8) + (sl << 5) + (r & 31);  // gate*256+sl*32+e

    float4 w[16];
    {
        const float4* Wg = (const float4*)(Whh + grow * HDIM + q * 64);
#pragma unroll
        for (int i = 0; i < 16; ++i) w[i] = Wg[i];
    }
    if (tid < 32) cl[tid] = 0.f;

    // prefetch gx for step 0 (only q==0 adds it)
    float gval = (q == 0) ? gx[(dir ? (S_LEN - 1) : 0) * GATES + grow] : 0.f;

    for (int t = 0; t < S_LEN; ++t) {
        const int tp = dir ? (S_LEN - 1 - t) : t;
        if (tid < 256) {
            if (t > 0) {
                const int tpp = dir ? (tp + 1) : (tp - 1);
                unsigned int b;
                do {
                    b = __hip_atomic_load(&hbits[tpp * 512 + dir * HDIM + tid],
                                          __ATOMIC_RELAXED, __HIP_MEMORY_SCOPE_AGENT);
                } while (b == SENT);
                hp[tid] = __uint_as_float(b);
            } else {
                hp[tid] = 0.f;
            }
        }
        __syncthreads();   // (a) hp ready / gl free

        // prefetch next step's gx (independent of h -> overlaps compute+poll)
        float gnext = 0.f;
        if (q == 0 && t + 1 < S_LEN) {
            const int tpn = dir ? (tp - 1) : (tp + 1);
            gnext = gx[tpn * GATES + grow];
        }

        // keep weights register-resident across iterations
#pragma unroll
        for (int i = 0; i < 16; ++i)
            asm volatile("" : "+v"(w[i].x), "+v"(w[i].y), "+v"(w[i].z), "+v"(w[i].w));

        const float4* hp4 = ((const float4*)hp) + q * 16;
        float4 a0 = {0.f, 0.f, 0.f, 0.f}, a1 = {0.f, 0.f, 0.f, 0.f};
#pragma unroll
        for (int i = 0; i < 16; i += 2) {
            float4 h0v = hp4[i];
            float4 h1v = hp4[i + 1];
            a0.x = fmaf(w[i].x, h0v.x, a0.x);
            a0.y = fmaf(w[i].y, h0v.y, a0.y);
            a0.z = fmaf(w[i].z, h0v.z, a0.z);
            a0.w = fmaf(w[i].w, h0v.w, a0.w);
            a1.x = fmaf(w[i + 1].x, h1v.x, a1.x);
            a1.y = fmaf(w[i + 1].y, h1v.y, a1.y);
            a1.z = fmaf(w[i + 1].z, h1v.z, a1.z);
            a1.w = fmaf(w[i + 1].w, h1v.w, a1.w);
        }
        float acc = ((a0.x + a1.x) + (a0.y + a1.y)) + ((a0.z + a1.z) + (a0.w + a1.w));
        acc += __shfl_xor(acc, 1);
        acc += __shfl_xor(acc, 2);
        if (q == 0) gl[r] = acc + gval;
        __syncthreads();   // (b) gl ready

        if (tid < 32) {
            float gi = gl[tid], gf = gl[32 + tid], gg = gl[64 + tid], go = gl[96 + tid];
            float si = __fdividef(1.f, 1.f + __expf(-gi));
            float sf = __fdividef(1.f, 1.f + __expf(-gf));
            float so = __fdividef(1.f, 1.f + __expf(-go));
            float eg = __expf(2.f * gg);
            float tg = 1.f - __fdividef(2.f, eg + 1.f);
            float cv = fmaf(sf, cl[tid], si * tg);
            cl[tid] = cv;
            float ec = __expf(2.f * cv);
            float tc = 1.f - __fdividef(2.f, ec + 1.f);
            float hv = so * tc;
            unsigned int ob = __float_as_uint(hv);
            if (ob == SENT) ob ^= 1u;           // never store the sentinel
            __hip_atomic_store(&hbits[tp * 512 + dir * HDIM + (sl << 5) + tid], ob,
                               __ATOMIC_RELAXED, __HIP_MEMORY_SCOPE_AGENT);
        }
        gval = gnext;
        // next-iteration barrier (a) orders gl/hp reuse
    }
}

// ---------------- pairwise scorer ----------------
__device__ __forceinline__ float tanh_fast(float x) {
    float e = __expf(2.f * x);
    return 1.f - __fdividef(2.f, e + 1.f);
}

__global__ __launch_bounds__(256) void scorer(
    const float* __restrict__ hA, const float* __restrict__ hB,
    const float* __restrict__ w2, const float* __restrict__ b2,
    float* __restrict__ out) {
    __shared__ float Al[32][129];
    __shared__ float Bl[32][129];
    __shared__ float w2s[128];
    const int t  = threadIdx.x;
    const int i0 = blockIdx.x * 32, j0 = blockIdx.y * 32;
    for (int idx = t; idx < 32 * 128; idx += 256) {
        int r = idx >> 7, k = idx & 127;
        Al[r][k] = hA[(i0 + r) * MLP + k];
        Bl[r][k] = hB[(j0 + r) * MLP + k];
    }
    if (t < 128) w2s[t] = w2[t];
    __syncthreads();

    const int j = t & 31, i2 = t >> 5;
    const float base = b2[0];
    float acc0 = base, acc1 = base, acc2 = base, acc3 = base;
#pragma unroll 4
    for (int k = 0; k < 128; ++k) {
        float bv = Bl[j][k];
        float wv = w2s[k];
        float y0 = Al[i2 * 4 + 0][k] + bv;
        float y1 = Al[i2 * 4 + 1][k] + bv;
        float y2 = Al[i2 * 4 + 2][k] + bv;
        float y3 = Al[i2 * 4 + 3][k] + bv;
        acc0 = fmaf(wv, tanh_fast(y0), acc0);
        acc1 = fmaf(wv, tanh_fast(y1), acc1);
        acc2 = fmaf(wv, tanh_fast(y2), acc2);
        acc3 = fmaf(wv, tanh_fast(y3), acc3);
    }
    const int jj = j0 + j;
    float accs[4] = {acc0, acc1, acc2, acc3};
#pragma unroll
    for (int ii = 0; ii < 4; ++ii) {
        int i = i0 + i2 * 4 + ii;
        out[i * S_LEN + jj] = (i == jj) ? 0.f : accs[ii];
    }
}

extern "C" void kernel_launch(void* const* d_in, const int* in_sizes, int n_in,
                              void* d_out, int out_size, void* d_ws, size_t ws_size,
                              hipStream_t stream) {
    (void)in_sizes; (void)n_in; (void)out_size; (void)ws_size;
    const int*   widx  = (const int*)d_in[0];
    const int*   pidx  = (const int*)d_in[1];
    const float* Ww    = (const float*)d_in[3];
    const float* Wp    = (const float*)d_in[4];
    const float* Wih0f = (const float*)d_in[5];
    const float* Whh0f = (const float*)d_in[6];
    const float* bih0f = (const float*)d_in[7];
    const float* bhh0f = (const float*)d_in[8];
    const float* Wih0b = (const float*)d_in[9];
    const float* Whh0b = (const float*)d_in[10];
    const float* bih0b = (const float*)d_in[11];
    const float* bhh0b = (const float*)d_in[12];
    const float* Wih1f = (const float*)d_in[13];
    const float* Whh1f = (const float*)d_in[14];
    const float* bih1f = (const float*)d_in[15];
    const float* bhh1f = (const float*)d_in[16];
    const float* Wih1b = (const float*)d_in[17];
    const float* Whh1b = (const float*)d_in[18];
    const float* bih1b = (const float*)d_in[19];
    const float* bhh1b = (const float*)d_in[20];
    const float* W1    = (const float*)d_in[21];
    const float* b1    = (const float*)d_in[22];
    const float* W2    = (const float*)d_in[23];
    const float* b2    = (const float*)d_in[24];

    float* ws  = (float*)d_ws;
    float* x0  = ws;                       // 768*128
    float* h0  = x0 + S_LEN * EMB;         // 768*512
    float* h1  = h0 + S_LEN * 512;         // 768*512
    float* gxf = h1 + S_LEN * 512;         // 768*1024
    float* gxb = gxf + S_LEN * GATES;      // 768*1024
    float* hA  = gxb + S_LEN * GATES;      // 768*128
    float* hB  = hA + S_LEN * MLP;         // 768*128

    // sentinel-fill h0 and h1 (contiguous) — the data-as-flag ready marker
    hipMemsetAsync(h0, 0xAA, 2 * S_LEN * 512 * sizeof(float), stream);

    embed_kernel<<<S_LEN, EMB, 0, stream>>>(widx, pidx, Ww, Wp, x0);

    dim3 gg(12, 16);
    gemm_bias<<<gg, 256, 0, stream>>>(x0, EMB, Wih0f, EMB, bih0f, bhh0f, gxf, GATES, EMB);
    gemm_bias<<<gg, 256, 0, stream>>>(x0, EMB, Wih0b, EMB, bih0b, bhh0b, gxb, GATES, EMB);
    lstm_rec<<<16, 512, 0, stream>>>(Whh0f, Whh0b, gxf, gxb, h0);

    gemm_bias<<<gg, 256, 0, stream>>>(h0, 512, Wih1f, 512, bih1f, bhh1f, gxf, GATES, 512);
    gemm_bias<<<gg, 256, 0, stream>>>(h0, 512, Wih1b, 512, bih1b, bhh1b, gxb, GATES, 512);
    lstm_rec<<<16, 512, 0, stream>>>(Whh1f, Whh1b, gxf, gxb, h1);

    dim3 ga(12, 2);
    gemm_bias<<<ga, 256, 0, stream>>>(h1, 512, W1,       1024, b1,      nullptr, hA, MLP, 512);
    gemm_bias<<<ga, 256, 0, stream>>>(h1, 512, W1 + 512, 1024, nullptr, nullptr, hB, MLP, 512);

    dim3 gs(24, 24);
    scorer<<<gs, 256, 0, stream>>>(hA, hB, W2, b2, (float*)d_out);
}

// Round 5
// 2854.414 us; speedup vs baseline: 1.3443x; 1.3443x over previous
//
#include <hip/hip_runtime.h>

#define S_LEN 768
#define EMB   128
#define HDIM  256
#define GATES 1024
#define MLP   128
#define SENT  0xAAAAAAAAu

// ---------------- embedding gather ----------------
__global__ void embed_kernel(const int* __restrict__ widx, const int* __restrict__ pidx,
                             const float* __restrict__ Ww, const float* __restrict__ Wp,
                             float* __restrict__ x0) {
    int t = blockIdx.x, k = threadIdx.x;
    float v;
    if (k < 100) v = Ww[widx[t] * 100 + k];
    else         v = Wp[pidx[t] * 28 + (k - 100)];
    x0[t * EMB + k] = v;
}

// ---------------- generic fp32 GEMM: C[M,N] = A[M,*] * B[N,*]^T + bias1 + bias2 ----------------
__global__ __launch_bounds__(256) void gemm_bias(
    const float* __restrict__ A, int lda,
    const float* __restrict__ B, int ldb,
    const float* __restrict__ bias1, const float* __restrict__ bias2,
    float* __restrict__ C, int ldc, int K) {
    __shared__ float As[32][65];
    __shared__ float Bs[32][65];
    const int t  = threadIdx.x;
    const int m0 = blockIdx.x * 64, n0 = blockIdx.y * 64;
    const int tm = t >> 4, tn = t & 15;
    float acc[4][4];
#pragma unroll
    for (int i = 0; i < 4; ++i)
#pragma unroll
        for (int j = 0; j < 4; ++j) acc[i][j] = 0.f;

    for (int k0 = 0; k0 < K; k0 += 32) {
#pragma unroll
        for (int l = 0; l < 8; ++l) {
            int idx = t + l * 256;
            int m = idx >> 5, kk = idx & 31;
            As[kk][m] = A[(m0 + m) * lda + k0 + kk];
            Bs[kk][m] = B[(n0 + m) * ldb + k0 + kk];
        }
        __syncthreads();
#pragma unroll
        for (int kk = 0; kk < 32; ++kk) {
            float a4[4], b4[4];
#pragma unroll
            for (int i = 0; i < 4; ++i) a4[i] = As[kk][tm * 4 + i];
#pragma unroll
            for (int j = 0; j < 4; ++j) b4[j] = Bs[kk][tn * 4 + j];
#pragma unroll
            for (int i = 0; i < 4; ++i)
#pragma unroll
                for (int j = 0; j < 4; ++j)
                    acc[i][j] = fmaf(a4[i], b4[j], acc[i][j]);
        }
        __syncthreads();
    }
    float bb[4];
#pragma unroll
    for (int j = 0; j < 4; ++j) {
        int n = n0 + tn * 4 + j;
        bb[j] = (bias1 ? bias1[n] : 0.f) + (bias2 ? bias2[n] : 0.f);
    }
#pragma unroll
    for (int i = 0; i < 4; ++i) {
        int m = m0 + tm * 4 + i;
        float4 o;
        o.x = acc[i][0] + bb[0];
        o.y = acc[i][1] + bb[1];
        o.z = acc[i][2] + bb[2];
        o.w = acc[i][3] + bb[3];
        *(float4*)(&C[m * ldc + n0 + tn * 4]) = o;
    }
}

// ---------------- LSTM recurrence, one layer, both directions ----------------
// 64 blocks x 256 threads: dir = bid&1, slice sl = bid>>1 (32 slices/dir).
// Block owns 8 h-outputs -> 32 gate rows -> 32KB of Whh staged ONCE in LDS
// (deterministic residency; R3/R4 showed the register allocator won't keep
// weight arrays in VGPRs). Thread t: local row lr=t>>3 (gate g=lr>>3, out
// e=lr&7), chunk q=t&3..7 -> 32 weights (8 float4) per thread per step, read
// from LDS conflict-free (per-lane-contiguous). hp chunks XOR-swizzled
// (j' = q*8 + (i^q)) so the 8 broadcast groups hit 8 distinct banks.
// Sync: data-as-flag through agent scope (h word != 0xAA sentinel).
__global__ __launch_bounds__(256, 1) void lstm_rec(
    const float* __restrict__ WhhF, const float* __restrict__ WhhB,
    const float* __restrict__ gxF, const float* __restrict__ gxB,
    float* __restrict__ hOut)        // [S][512]; fwd cols 0..255, bwd 256..511
{
    __shared__ float4 wlds[8 * 256];     // [i][t] 32KB
    __shared__ float  hps[256];          // swizzled h_prev
    __shared__ float  gl[32];
    const int tid = threadIdx.x;
    const int dir = blockIdx.x & 1;
    const int sl  = blockIdx.x >> 1;
    const float* __restrict__ Whh = dir ? WhhB : WhhF;
    const float* __restrict__ gx  = dir ? gxB  : gxF;
    unsigned int* hbits = (unsigned int*)hOut;

    const int lr = tid >> 3, q = tid & 7;            // row 0..31, chunk 0..7
    const int grow = (lr >> 3) * 256 + sl * 8 + (lr & 7);  // gate*256 + sl*8 + e

    // stage Whh slice into LDS: thread t's 8 chunks -> wlds[i*256+t]
    {
        const float4* Wg = (const float4*)(Whh + grow * HDIM + q * 32);
#pragma unroll
        for (int i = 0; i < 8; ++i) wlds[i * 256 + tid] = Wg[i];
    }

    float creg = 0.f;                                // c-state (threads 0..7 use it)
    float gval = (q == 0) ? gx[(dir ? (S_LEN - 1) : 0) * GATES + grow] : 0.f;

    for (int t = 0; t < S_LEN; ++t) {
        const int tp = dir ? (S_LEN - 1 - t) : t;
        {
            float hv;
            if (t > 0) {
                const int tpp = dir ? (tp + 1) : (tp - 1);
                unsigned int b;
                do {
                    b = __hip_atomic_load(&hbits[tpp * 512 + dir * HDIM + tid],
                                          __ATOMIC_RELAXED, __HIP_MEMORY_SCOPE_AGENT);
                } while (b == SENT);
                hv = __uint_as_float(b);
            } else {
                hv = 0.f;
            }
            // swizzled store: element tid -> float4 j=tid>>2 (qq=tid>>5, ii=(tid>>2)&7)
            const int qq = tid >> 5, ii = (tid >> 2) & 7;
            hps[(qq * 8 + (ii ^ qq)) * 4 + (tid & 3)] = hv;
        }
        __syncthreads();   // (a) hps/wlds ready, gl free

        // prefetch next step's gx (independent of h -> overlaps compute+poll)
        float gnext = 0.f;
        if (q == 0 && t + 1 < S_LEN) {
            const int tpn = dir ? (tp - 1) : (tp + 1);
            gnext = gx[tpn * GATES + grow];
        }

        const float4* hp4 = (const float4*)hps;
        float4 a = {0.f, 0.f, 0.f, 0.f};
#pragma unroll
        for (int i = 0; i < 8; ++i) {
            float4 wv = wlds[i * 256 + tid];
            float4 hv = hp4[q * 8 + (i ^ q)];
            a.x = fmaf(wv.x, hv.x, a.x);
            a.y = fmaf(wv.y, hv.y, a.y);
            a.z = fmaf(wv.z, hv.z, a.z);
            a.w = fmaf(wv.w, hv.w, a.w);
        }
        float acc = (a.x + a.y) + (a.z + a.w);
        acc += __shfl_xor(acc, 1);
        acc += __shfl_xor(acc, 2);
        acc += __shfl_xor(acc, 4);
        if (q == 0) gl[lr] = acc + gval;
        __syncthreads();   // (b) gl ready

        if (tid < 8) {
            float gi = gl[tid], gf = gl[8 + tid], gg = gl[16 + tid], go = gl[24 + tid];
            float si = __fdividef(1.f, 1.f + __expf(-gi));
            float sf = __fdividef(1.f, 1.f + __expf(-gf));
            float so = __fdividef(1.f, 1.f + __expf(-go));
            float eg = __expf(2.f * gg);
            float tg = 1.f - __fdividef(2.f, eg + 1.f);
            creg = fmaf(sf, creg, si * tg);
            float ec = __expf(2.f * creg);
            float tc = 1.f - __fdividef(2.f, ec + 1.f);
            float hv = so * tc;
            unsigned int ob = __float_as_uint(hv);
            if (ob == SENT) ob ^= 1u;           // never store the sentinel
            __hip_atomic_store(&hbits[tp * 512 + dir * HDIM + sl * 8 + tid], ob,
                               __ATOMIC_RELAXED, __HIP_MEMORY_SCOPE_AGENT);
        }
        gval = gnext;
        // next-iteration barrier (a) orders hps/gl reuse
    }
}

// ---------------- pairwise scorer ----------------
__device__ __forceinline__ float tanh_fast(float x) {
    float e = __expf(2.f * x);
    return 1.f - __fdividef(2.f, e + 1.f);
}

__global__ __launch_bounds__(256) void scorer(
    const float* __restrict__ hA, const float* __restrict__ hB,
    const float* __restrict__ w2, const float* __restrict__ b2,
    float* __restrict__ out) {
    __shared__ float Al[32][129];
    __shared__ float Bl[32][129];
    __shared__ float w2s[128];
    const int t  = threadIdx.x;
    const int i0 = blockIdx.x * 32, j0 = blockIdx.y * 32;
    for (int idx = t; idx < 32 * 128; idx += 256) {
        int r = idx >> 7, k = idx & 127;
        Al[r][k] = hA[(i0 + r) * MLP + k];
        Bl[r][k] = hB[(j0 + r) * MLP + k];
    }
    if (t < 128) w2s[t] = w2[t];
    __syncthreads();

    const int j = t & 31, i2 = t >> 5;
    const float base = b2[0];
    float acc0 = base, acc1 = base, acc2 = base, acc3 = base;
#pragma unroll 4
    for (int k = 0; k < 128; ++k) {
        float bv = Bl[j][k];
        float wv = w2s[k];
        float y0 = Al[i2 * 4 + 0][k] + bv;
        float y1 = Al[i2 * 4 + 1][k] + bv;
        float y2 = Al[i2 * 4 + 2][k] + bv;
        float y3 = Al[i2 * 4 + 3][k] + bv;
        acc0 = fmaf(wv, tanh_fast(y0), acc0);
        acc1 = fmaf(wv, tanh_fast(y1), acc1);
        acc2 = fmaf(wv, tanh_fast(y2), acc2);
        acc3 = fmaf(wv, tanh_fast(y3), acc3);
    }
    const int jj = j0 + j;
    float accs[4] = {acc0, acc1, acc2, acc3};
#pragma unroll
    for (int ii = 0; ii < 4; ++ii) {
        int i = i0 + i2 * 4 + ii;
        out[i * S_LEN + jj] = (i == jj) ? 0.f : accs[ii];
    }
}

extern "C" void kernel_launch(void* const* d_in, const int* in_sizes, int n_in,
                              void* d_out, int out_size, void* d_ws, size_t ws_size,
                              hipStream_t stream) {
    (void)in_sizes; (void)n_in; (void)out_size; (void)ws_size;
    const int*   widx  = (const int*)d_in[0];
    const int*   pidx  = (const int*)d_in[1];
    const float* Ww    = (const float*)d_in[3];
    const float* Wp    = (const float*)d_in[4];
    const float* Wih0f = (const float*)d_in[5];
    const float* Whh0f = (const float*)d_in[6];
    const float* bih0f = (const float*)d_in[7];
    const float* bhh0f = (const float*)d_in[8];
    const float* Wih0b = (const float*)d_in[9];
    const float* Whh0b = (const float*)d_in[10];
    const float* bih0b = (const float*)d_in[11];
    const float* bhh0b = (const float*)d_in[12];
    const float* Wih1f = (const float*)d_in[13];
    const float* Whh1f = (const float*)d_in[14];
    const float* bih1f = (const float*)d_in[15];
    const float* bhh1f = (const float*)d_in[16];
    const float* Wih1b = (const float*)d_in[17];
    const float* Whh1b = (const float*)d_in[18];
    const float* bih1b = (const float*)d_in[19];
    const float* bhh1b = (const float*)d_in[20];
    const float* W1    = (const float*)d_in[21];
    const float* b1    = (const float*)d_in[22];
    const float* W2    = (const float*)d_in[23];
    const float* b2    = (const float*)d_in[24];

    float* ws  = (float*)d_ws;
    float* x0  = ws;                       // 768*128
    float* h0  = x0 + S_LEN * EMB;         // 768*512
    float* h1  = h0 + S_LEN * 512;         // 768*512
    float* gxf = h1 + S_LEN * 512;         // 768*1024
    float* gxb = gxf + S_LEN * GATES;      // 768*1024
    float* hA  = gxb + S_LEN * GATES;      // 768*128
    float* hB  = hA + S_LEN * MLP;         // 768*128

    // sentinel-fill h0 and h1 (contiguous) — the data-as-flag ready marker
    hipMemsetAsync(h0, 0xAA, 2 * S_LEN * 512 * sizeof(float), stream);

    embed_kernel<<<S_LEN, EMB, 0, stream>>>(widx, pidx, Ww, Wp, x0);

    dim3 gg(12, 16);
    gemm_bias<<<gg, 256, 0, stream>>>(x0, EMB, Wih0f, EMB, bih0f, bhh0f, gxf, GATES, EMB);
    gemm_bias<<<gg, 256, 0, stream>>>(x0, EMB, Wih0b, EMB, bih0b, bhh0b, gxb, GATES, EMB);
    lstm_rec<<<64, 256, 0, stream>>>(Whh0f, Whh0b, gxf, gxb, h0);

    gemm_bias<<<gg, 256, 0, stream>>>(h0, 512, Wih1f, 512, bih1f, bhh1f, gxf, GATES, 512);
    gemm_bias<<<gg, 256, 0, stream>>>(h0, 512, Wih1b, 512, bih1b, bhh1b, gxb, GATES, 512);
    lstm_rec<<<64, 256, 0, stream>>>(Whh1f, Whh1b, gxf, gxb, h1);

    dim3 ga(12, 2);
    gemm_bias<<<ga, 256, 0, stream>>>(h1, 512, W1,       1024, b1,      nullptr, hA, MLP, 512);
    gemm_bias<<<ga, 256, 0, stream>>>(h1, 512, W1 + 512, 1024, nullptr, nullptr, hB, MLP, 512);

    dim3 gs(24, 24);
    scorer<<<gs, 256, 0, stream>>>(hA, hB, W2, b2, (float*)d_out);
}